// Round 1
// 333.617 us; speedup vs baseline: 1.0223x; 1.0223x over previous
//
#include <hip/hip_runtime.h>

// ParallelExperts MoE, fused token-major formulation.
// out[t] = gates[t,0] * x[t] @ W[e(2t)]^T + gates[t,1] * x[t] @ W[e(2t+1)]^T
// N=262144, k=2, E=8, D=128.
//
// prep_kernel: (a) invert the sorted permutation -> per-slot expert byte
//              inv[ssi[p]] = sei[p]; (b) convert weights fp32 -> f16 (halves
//              B-fragment L2 traffic). Workspace use: 0.75 MB (was 134 MB).
// moe_fused_kernel: each block owns 64 consecutive tokens (128 slots).
//   - coalesced read of 64 input rows -> LDS f16
//   - block-local counting sort of the 128 slots by expert (LDS atomics;
//     run boundaries come analytically from the prefix sums)
//   - MFMA 16x16x32_f16 over sorted rows: per expert run, load B fragments
//     once, masked A rows at run boundaries (A-row indirection via atok[])
//   - stage g*y into LDS (reusing the A buffer), then combine the token's
//     two slots and write out[t] fully coalesced in f32. No ws round-trip,
//     no second big kernel.

#define D       128
#define TB      64       // tokens per block
#define SLOTS   128      // slots per block (k=2)
#define LSTR    136      // LDS row stride in f16 (272 B, 16B-aligned rows)
#define NTOK    262144
#define NK      (NTOK * 2)
#define NEXP    8

typedef _Float16 halfx8 __attribute__((ext_vector_type(8)));
typedef _Float16 halfx4 __attribute__((ext_vector_type(4)));
typedef _Float16 halfx2 __attribute__((ext_vector_type(2)));
typedef float    floatx4 __attribute__((ext_vector_type(4)));

// blocks [0, 2048): inv[ssi[p]] = sei[p]   (slot -> expert id, 1 byte)
// blocks [2048, 2176): weight fp32 -> f16  (8*128*128 = 131072 elements)
__global__ __launch_bounds__(256)
void prep_kernel(const int* __restrict__ sei, const int* __restrict__ ssi,
                 const float* __restrict__ weight,
                 unsigned char* __restrict__ inv, _Float16* __restrict__ wh)
{
    const int b = blockIdx.x, tid = threadIdx.x;
    if (b < NK / 256) {
        const int p = b * 256 + tid;
        inv[ssi[p]] = (unsigned char)sei[p];
    } else {
        const int i = ((b - NK / 256) * 256 + tid) * 4;
        float4 v = *(const float4*)(weight + i);
        halfx4 h = { (_Float16)v.x, (_Float16)v.y, (_Float16)v.z, (_Float16)v.w };
        *(halfx4*)(wh + i) = h;
    }
}

__global__ __launch_bounds__(256, 4)
void moe_fused_kernel(const float* __restrict__ inputs,
                      const _Float16* __restrict__ wh,
                      const float* __restrict__ gates,
                      const unsigned char* __restrict__ inv,
                      float* __restrict__ out)
{
    // Rows 0..63 hold the A-tile (tokens, f16); after MFMA the whole buffer
    // is reused as Y (128 sorted slot rows of g*y, f16). Same stride.
    __shared__ _Float16 As[SLOTS * LSTR];
    __shared__ int   atok[SLOTS];    // sorted pos -> local token (slot>>1)
    __shared__ int   posOf[SLOTS];   // local slot -> sorted pos
    __shared__ float gs[SLOTS];      // sorted pos -> gate
    __shared__ int   cnt[NEXP];
    __shared__ int   ebase[NEXP + 1];

    const int tid = threadIdx.x;
    const int t0  = blockIdx.x * TB;

    if (tid < NEXP) cnt[tid] = 0;
    __syncthreads();

    // --- counting-sort pass 1: count + grab rank (atomic return value) ---
    int myE = 0, myR = 0; float myG = 0.f;
    if (tid < SLOTS) {
        myE = inv[(size_t)t0 * 2 + tid];      // 128 contiguous bytes
        myG = gates[(size_t)t0 * 2 + tid];    // 128 contiguous floats
        myR = atomicAdd(&cnt[myE], 1);
    }

    // --- stage 64 token rows, fully coalesced, fp32 -> f16 into LDS ---
    #pragma unroll
    for (int it = 0; it < 8; ++it) {
        const int id = it * 256 + tid;        // 0..2047 float4 slots
        const int r  = id >> 5;               // token row 0..63
        const int c4 = id & 31;               // float4 column
        float4 v = ((const float4*)inputs)[(size_t)(t0 + r) * 32 + c4];
        halfx4 h = { (_Float16)v.x, (_Float16)v.y, (_Float16)v.z, (_Float16)v.w };
        *(halfx4*)&As[r * LSTR + c4 * 4] = h;
    }
    __syncthreads();

    // --- prefix sums: run e occupies sorted rows [ebase[e], ebase[e+1]) ---
    if (tid == 0) {
        int a = 0;
        #pragma unroll
        for (int e = 0; e < NEXP; ++e) { ebase[e] = a; a += cnt[e]; }
        ebase[NEXP] = a;                      // == SLOTS
    }
    __syncthreads();

    // --- counting-sort pass 2: placement ---
    if (tid < SLOTS) {
        const int p = ebase[myE] + myR;
        posOf[tid] = p;
        atok[p]    = tid >> 1;                // k == 2
        gs[p]      = myG;
    }
    __syncthreads();

    const int lane = tid & 63;
    const int w    = tid >> 6;       // wave 0..3
    const int m    = lane & 15;
    const int q    = lane >> 4;
    const int c0   = w * 32;         // wave's output-column base

    // A-row indirection offsets, hoisted (expert-independent)
    int aoff[8];
    #pragma unroll
    for (int rt = 0; rt < 8; ++rt) aoff[rt] = atok[rt * 16 + m] * LSTR;

    floatx4 acc[8][2];
    #pragma unroll
    for (int rt = 0; rt < 8; ++rt) {
        acc[rt][0] = {0.f, 0.f, 0.f, 0.f};
        acc[rt][1] = {0.f, 0.f, 0.f, 0.f};
    }

    // --- per-expert runs: load B fragments once, masked A at boundaries ---
    for (int e = 0; e < NEXP; ++e) {
        const int s0 = ebase[e], s1 = ebase[e + 1];
        if (s0 == s1) continue;               // uniform branch, empty run

        halfx8 bf[2][4];
        #pragma unroll
        for (int ct = 0; ct < 2; ++ct) {
            const _Float16* wrow = wh + (size_t)e * (D * D)
                                      + (size_t)(c0 + 2 * m + ct) * D;
            #pragma unroll
            for (int ks = 0; ks < 4; ++ks)
                bf[ct][ks] = *(const halfx8*)(wrow + ks * 32 + q * 8);
        }

        const int rt_lo = s0 >> 4, rt_hi = (s1 - 1) >> 4;
        #pragma unroll
        for (int rt = 0; rt < 8; ++rt) {      // static acc indexing
            if (rt < rt_lo || rt > rt_hi) continue;   // uniform skip
            const int row = rt * 16 + m;
            const bool in = (row >= s0) && (row < s1);
            #pragma unroll
            for (int ks = 0; ks < 4; ++ks) {
                const int kk = ks * 32 + q * 8;
                halfx8 a = {0, 0, 0, 0, 0, 0, 0, 0};
                if (in) a = *(const halfx8*)&As[aoff[rt] + kk];
                acc[rt][0] = __builtin_amdgcn_mfma_f32_16x16x32_f16(a, bf[0][ks], acc[rt][0], 0, 0, 0);
                acc[rt][1] = __builtin_amdgcn_mfma_f32_16x16x32_f16(a, bf[1][ks], acc[rt][1], 0, 0, 0);
            }
        }
    }

    __syncthreads();                 // all A reads done — safe to reuse as Y
    _Float16* Y = As;

    // Stage g*y: D row = rt*16 + q*4 + r (sorted pos); lane cols c0+2m(+1).
    #pragma unroll
    for (int rt = 0; rt < 8; ++rt) {
        #pragma unroll
        for (int r = 0; r < 4; ++r) {
            const int row = rt * 16 + q * 4 + r;
            const float g = gs[row];
            halfx2 h = { (_Float16)(acc[rt][0][r] * g),
                         (_Float16)(acc[rt][1][r] * g) };
            *(halfx2*)&Y[row * LSTR + c0 + 2 * m] = h;
        }
    }
    __syncthreads();

    // Combine the token's two slots and write out, fully coalesced:
    // 16 threads per row x 32 B = one 512 B burst per token row.
    #pragma unroll
    for (int it = 0; it < 4; ++it) {
        const int idx = it * 256 + tid;       // 0..1023
        const int r   = idx >> 4;             // token row 0..63
        const int c8  = (idx & 15) * 8;       // f32 col 0..120
        const int p0  = posOf[2 * r];
        const int p1  = posOf[2 * r + 1];
        halfx8 a = *(const halfx8*)&Y[p0 * LSTR + c8];
        halfx8 b = *(const halfx8*)&Y[p1 * LSTR + c8];
        float* dst = out + (size_t)(t0 + r) * D + c8;
        float4 lo = { (float)a[0] + (float)b[0], (float)a[1] + (float)b[1],
                      (float)a[2] + (float)b[2], (float)a[3] + (float)b[3] };
        float4 hi = { (float)a[4] + (float)b[4], (float)a[5] + (float)b[5],
                      (float)a[6] + (float)b[6], (float)a[7] + (float)b[7] };
        *(float4*)dst = lo;
        *(float4*)(dst + 4) = hi;
    }
}

extern "C" void kernel_launch(void* const* d_in, const int* in_sizes, int n_in,
                              void* d_out, int out_size, void* d_ws, size_t ws_size,
                              hipStream_t stream)
{
    const float* inputs = (const float*)d_in[0];   // [N, 128] fp32
    const float* weight = (const float*)d_in[1];   // [8, 128, 128] fp32
    const float* gates  = (const float*)d_in[2];   // [N, 2] fp32
    const int*   sei    = (const int*)d_in[4];     // sorted_expert_idxs [N*2]
    const int*   ssi    = (const int*)d_in[5];     // sorted_scattered_idxs [N*2]
    float* out = (float*)d_out;

    unsigned char* inv = (unsigned char*)d_ws;                 // NK bytes
    _Float16*      wh  = (_Float16*)((char*)d_ws + NK);        // 256 KB f16 weights

    prep_kernel<<<dim3(NK / 256 + (NEXP * D * D) / 1024), dim3(256), 0, stream>>>(
        sei, ssi, weight, inv, wh);

    moe_fused_kernel<<<dim3(NTOK / TB), dim3(256), 0, stream>>>(
        inputs, wh, gates, inv, out);
}